// Round 19
// baseline (347.636 us; speedup 1.0000x reference)
//
#include <hip/hip_runtime.h>

// ---------------------------------------------------------------------------
// MR_GNN: 2x (RGCN + GroupEnhance) + linear head.
// R18 -> R19: partition is the last big kernel (42us, VALU 1.25%, occupancy
// 15% = grid-limited at 489 blocks). (a) PART_EPB 2048->1024: 977 blocks,
// 2x occupancy (R6 mechanism); reserve atomics ~1000/addr, far below R5's
// failure mode. (b) single-pass register prefetch: each thread loads its 4
// edges' (dst,src,rel,w) ONCE into named regs, reused for LDS hist AND
// scatter -- deletes pass-2's re-read of ei/et/ew. (c) packed 8B record
// rec=(w, local10<<22|src) (N << 2^22; local=(dst&255)*4+rel) replaces the
// 12B recA/recB pair: one store per edge, -1/3 write, -4MB fill fetch.
// Gathers, rgcn_mfma, group_mfma, packs unchanged from R18 (338.9us, 5.7e-6).
// ---------------------------------------------------------------------------

#define PART_EPB 1024  // edges per partition/hist block (256 thr x 4)

using short8 = __attribute__((ext_vector_type(8))) short;
using f32x4v = __attribute__((ext_vector_type(4))) float;

// ---- CSR build, pass A1: per-bucket edge counts (bucket = dst >> 8) ----
__global__ __launch_bounds__(256) void bucket_hist(const int* __restrict__ ei,
                                                   int* __restrict__ bcnt,
                                                   int E, int NB) {
    __shared__ int h[1024];
    for (int i = threadIdx.x; i < 1024; i += 256) h[i] = 0;
    __syncthreads();
    int base = blockIdx.x * PART_EPB;
#pragma unroll
    for (int k = 0; k < PART_EPB / 256; ++k) {
        int e = base + k * 256 + threadIdx.x;
        if (e < E) atomicAdd(&h[ei[E + e] >> 8], 1);
    }
    __syncthreads();
    for (int i = threadIdx.x; i < NB; i += 256)
        if (h[i]) atomicAdd(&bcnt[i], h[i]);
}

// ---- pass A-scan: exclusive scan of NB (<=1024) bucket counts ----
__global__ __launch_bounds__(1024) void bucket_scan(const int* __restrict__ bcnt,
                                                    int* __restrict__ bofs,
                                                    int* __restrict__ bcur,
                                                    int NB, int E) {
    __shared__ int lds[1024];
    int tid = threadIdx.x;
    int v = (tid < NB) ? bcnt[tid] : 0;
    lds[tid] = v;
    __syncthreads();
    int acc = v;
    for (int off = 1; off < 1024; off <<= 1) {
        int t = (tid >= off) ? lds[tid - off] : 0;
        __syncthreads();
        acc += t;
        lds[tid] = acc;
        __syncthreads();
    }
    int excl = acc - v;
    if (tid < NB) { bofs[tid] = excl; bcur[tid] = excl; }
    if (tid == 0) bofs[NB] = E;
}

// ---- pass A2: block-aggregated partition into bucket streams ----
// Register-prefetched single pass: each thread owns 4 edges; (dst,src,rel,w)
// loaded once, reused for LDS hist and scatter. rec = (w, local<<22 | src),
// local = (dst&255)*4 + rel (requires N < 2^22).
__global__ __launch_bounds__(256) void partition(const int* __restrict__ ei,
                                                 const int* __restrict__ et,
                                                 const float* __restrict__ ew,
                                                 int* __restrict__ gcur,
                                                 int2* __restrict__ rec,
                                                 int E, int NB) {
    __shared__ int hist[1024];
    __shared__ int base[1024];
    const int tid = threadIdx.x;
    const int e0 = blockIdx.x * PART_EPB + tid;
    const int e1 = e0 + 256, e2 = e0 + 512, e3 = e0 + 768;
    int d0 = 0, d1 = 0, d2 = 0, d3 = 0;
    int s0 = 0, s1 = 0, s2 = 0, s3 = 0;
    int t0 = 0, t1 = 0, t2 = 0, t3 = 0;
    int w0 = 0, w1 = 0, w2 = 0, w3 = 0;
    if (e0 < E) { d0 = ei[E + e0]; s0 = ei[e0]; t0 = et[e0]; w0 = __float_as_int(ew[e0]); }
    if (e1 < E) { d1 = ei[E + e1]; s1 = ei[e1]; t1 = et[e1]; w1 = __float_as_int(ew[e1]); }
    if (e2 < E) { d2 = ei[E + e2]; s2 = ei[e2]; t2 = et[e2]; w2 = __float_as_int(ew[e2]); }
    if (e3 < E) { d3 = ei[E + e3]; s3 = ei[e3]; t3 = et[e3]; w3 = __float_as_int(ew[e3]); }
    for (int i = tid; i < 1024; i += 256) hist[i] = 0;
    __syncthreads();
    if (e0 < E) atomicAdd(&hist[d0 >> 8], 1);
    if (e1 < E) atomicAdd(&hist[d1 >> 8], 1);
    if (e2 < E) atomicAdd(&hist[d2 >> 8], 1);
    if (e3 < E) atomicAdd(&hist[d3 >> 8], 1);
    __syncthreads();
    for (int i = tid; i < NB; i += 256) {
        int h = hist[i];
        base[i] = h ? atomicAdd(&gcur[i], h) : 0;
    }
    __syncthreads();
    for (int i = tid; i < 1024; i += 256) hist[i] = 0;  // reuse as run cursor
    __syncthreads();
    if (e0 < E) { int b = d0 >> 8; int p = base[b] + atomicAdd(&hist[b], 1);
                  rec[p] = make_int2(w0, (((d0 & 255) << 2 | t0) << 22) | s0); }
    if (e1 < E) { int b = d1 >> 8; int p = base[b] + atomicAdd(&hist[b], 1);
                  rec[p] = make_int2(w1, (((d1 & 255) << 2 | t1) << 22) | s1); }
    if (e2 < E) { int b = d2 >> 8; int p = base[b] + atomicAdd(&hist[b], 1);
                  rec[p] = make_int2(w2, (((d2 & 255) << 2 | t2) << 22) | s2); }
    if (e3 < E) { int b = d3 >> 8; int p = base[b] + atomicAdd(&hist[b], 1);
                  rec[p] = make_int2(w3, (((d3 & 255) << 2 | t3) << 22) | s3); }
}

// ---- pass B: per-bucket (node,rel) hist + scan in LDS, write rp2 + pw ----
__global__ __launch_bounds__(256) void bucket_fill(
    const int2* __restrict__ rec, const int* __restrict__ bofs,
    int* __restrict__ rp2, int2* __restrict__ pw, int N) {
    __shared__ int cnt[1024];
    __shared__ int cur[1024];
    __shared__ int wsum[4];
    const int b = blockIdx.x;
    const int tid = threadIdx.x;
    const int beg = bofs[b], end = bofs[b + 1];
    const int rebase = b << 10;  // base index in (dst*4+rel) space
    for (int j = 0; j < 4; ++j) cnt[tid * 4 + j] = 0;
    __syncthreads();
    for (int i = beg + tid; i < end; i += 256)
        atomicAdd(&cnt[((unsigned)rec[i].y) >> 22], 1);
    __syncthreads();
    int v[4];
    int s = 0;
#pragma unroll
    for (int j = 0; j < 4; ++j) { v[j] = cnt[tid * 4 + j]; s += v[j]; }
    int lane = tid & 63, wid = tid >> 6;
    int ws = s;
#pragma unroll
    for (int off = 1; off < 64; off <<= 1) {
        int t = __shfl_up(ws, off);
        if (lane >= off) ws += t;
    }
    if (lane == 63) wsum[wid] = ws;
    __syncthreads();
    int wb = 0;
    for (int w = 0; w < wid; ++w) wb += wsum[w];
    int run = beg + wb + ws - s;
#pragma unroll
    for (int j = 0; j < 4; ++j) {
        int idx = rebase + tid * 4 + j;
        if (idx <= 4 * N) rp2[idx] = run;
        cur[tid * 4 + j] = run;
        run += v[j];
    }
    __syncthreads();
    for (int i = beg + tid; i < end; i += 256) {
        int2 r = rec[i];
        int l = ((unsigned)r.y) >> 22;
        int p = atomicAdd(&cur[l], 1);
        pw[p] = make_int2(r.y & 0x3FFFFF, r.x);
    }
}

__device__ __forceinline__ float4 quad_reduce(float4 a) {
#pragma unroll
    for (int off = 16; off < 64; off <<= 1) {
        a.x += __shfl_xor(a.x, off);
        a.y += __shfl_xor(a.y, off);
        a.z += __shfl_xor(a.z, off);
        a.w += __shfl_xor(a.w, off);
    }
    return a;
}

__device__ __forceinline__ void fma4(float4& a, float w, const float4& x) {
    a.x += w * x.x; a.y += w * x.y; a.z += w * x.z; a.w += w * x.w;
}

__device__ __forceinline__ unsigned short f2bf(float f) {
    unsigned u = __float_as_uint(f);
    unsigned r = u + 0x7fffu + ((u >> 16) & 1u);  // round-to-nearest-even
    return (unsigned short)(r >> 16);
}

__device__ __forceinline__ float bf2f(unsigned short h) {
    return __uint_as_float(((unsigned)h) << 16);
}

__device__ __forceinline__ float4 bf2f4(ushort4 h) {
    return make_float4(bf2f(h.x), bf2f(h.y), bf2f(h.z), bf2f(h.w));
}

// ---- fp32 -> bf16 table cast (for x; sequential, ~2us) ----
__global__ __launch_bounds__(256) void cast_bf16(const float* __restrict__ in,
                                                 unsigned short* __restrict__ out,
                                                 int n4) {
    int i = blockIdx.x * 256 + threadIdx.x;
    if (i >= n4) return;
    float4 v = reinterpret_cast<const float4*>(in)[i];
    reinterpret_cast<ushort4*>(out)[i] =
        make_ushort4(f2bf(v.x), f2bf(v.y), f2bf(v.z), f2bf(v.w));
}

// ---- pack B_cat = [W0 (64x64); Wr (4x64x64)] (K=320 x N=64) into bf16
// MFMA B-fragment order: out[((t*4+n4)*4+kg)*128 + col*8 + j] =
// bf16(B_cat[t*32+kg*8+j][n4*16+col]).  20480 elements. ----
__global__ __launch_bounds__(256) void pack_w(const float* __restrict__ W0,
                                              const float* __restrict__ Wr,
                                              unsigned short* __restrict__ out) {
    int i = blockIdx.x * 256 + threadIdx.x;
    if (i >= 20480) return;
    int j = i & 7, col = (i >> 3) & 15, kg = (i >> 7) & 3, n4 = (i >> 9) & 3, t = i >> 11;
    int k = t * 32 + kg * 8 + j;
    int n = n4 * 16 + col;
    float v = (k < 64) ? W0[k * 64 + n] : Wr[(size_t)(k - 64) * 64 + n];
    out[i] = f2bf(v);
}

// ---- same pack for a single 64x64 weight (K=64): 4096 elements ----
__global__ __launch_bounds__(256) void pack_w64(const float* __restrict__ W,
                                                unsigned short* __restrict__ out) {
    int i = blockIdx.x * 256 + threadIdx.x;
    if (i >= 4096) return;
    int j = i & 7, col = (i >> 3) & 15, kg = (i >> 7) & 3, n4 = (i >> 9) & 3, t = i >> 11;
    int k = t * 32 + kg * 8 + j;
    int n = n4 * 16 + col;
    out[i] = f2bf(W[k * 64 + n]);
}

// ---------------------------------------------------------------------------
// Unified-range gather (R7 structure; bf16 input table; proven in R13).
// REL=1: masked per-relation accumulators -> bf16 out (ushort N x 256).
// REL=0: 4 chains summed -> bf16 out (ushort N x 64).
// ---------------------------------------------------------------------------
template <int REL>
__global__ __launch_bounds__(256) void gather_k(
    const unsigned short* __restrict__ Xb, const int* __restrict__ rp2,
    const int2* __restrict__ pw, unsigned short* __restrict__ outp, int N) {
    int node = blockIdx.x * 4 + (threadIdx.x >> 6);
    if (node >= N) return;
    int lane = threadIdx.x & 63;
    int q = lane >> 4, m = lane & 15;
    const int4 sv = *reinterpret_cast<const int4*>(rp2 + node * 4);
    const int s0 = sv.x, s1 = sv.y, s2 = sv.z, s3 = sv.w;
    const int s4 = rp2[node * 4 + 4];
    float4 A0 = make_float4(0.f, 0.f, 0.f, 0.f);
    float4 A1 = make_float4(0.f, 0.f, 0.f, 0.f);
    float4 A2 = make_float4(0.f, 0.f, 0.f, 0.f);
    float4 A3 = make_float4(0.f, 0.f, 0.f, 0.f);

    auto accum = [&](int idx, int slot, int2 e, const float4& xv) {
        float w = __int_as_float(e.y);
        if (REL) {
            fma4(A0, (idx < s1) ? w : 0.f, xv);
            fma4(A1, (idx >= s1 && idx < s2) ? w : 0.f, xv);
            fma4(A2, (idx >= s2 && idx < s3) ? w : 0.f, xv);
            fma4(A3, (idx >= s3) ? w : 0.f, xv);
        } else {
            if (slot == 0) fma4(A0, w, xv);
            else if (slot == 1) fma4(A1, w, xv);
            else if (slot == 2) fma4(A2, w, xv);
            else fma4(A3, w, xv);
        }
    };

    int i = s0 + q;
    for (; i + 12 < s4; i += 16) {  // 4 gathers in flight
        int2 e0 = pw[i];
        int2 e1 = pw[i + 4];
        int2 e2 = pw[i + 8];
        int2 e3 = pw[i + 12];
        ushort4 h0 = *reinterpret_cast<const ushort4*>(Xb + (size_t)e0.x * 64 + m * 4);
        ushort4 h1 = *reinterpret_cast<const ushort4*>(Xb + (size_t)e1.x * 64 + m * 4);
        ushort4 h2 = *reinterpret_cast<const ushort4*>(Xb + (size_t)e2.x * 64 + m * 4);
        ushort4 h3 = *reinterpret_cast<const ushort4*>(Xb + (size_t)e3.x * 64 + m * 4);
        accum(i, 0, e0, bf2f4(h0));
        accum(i + 4, 1, e1, bf2f4(h1));
        accum(i + 8, 2, e2, bf2f4(h2));
        accum(i + 12, 3, e3, bf2f4(h3));
    }
    for (; i + 4 < s4; i += 8) {  // 2 in flight
        int2 e0 = pw[i];
        int2 e1 = pw[i + 4];
        ushort4 h0 = *reinterpret_cast<const ushort4*>(Xb + (size_t)e0.x * 64 + m * 4);
        ushort4 h1 = *reinterpret_cast<const ushort4*>(Xb + (size_t)e1.x * 64 + m * 4);
        accum(i, 0, e0, bf2f4(h0));
        accum(i + 4, 1, e1, bf2f4(h1));
    }
    if (i < s4) {
        int2 e0 = pw[i];
        ushort4 h0 = *reinterpret_cast<const ushort4*>(Xb + (size_t)e0.x * 64 + m * 4);
        accum(i, 0, e0, bf2f4(h0));
    }

    if (REL) {
        A0 = quad_reduce(A0);
        A1 = quad_reduce(A1);
        A2 = quad_reduce(A2);
        A3 = quad_reduce(A3);
        float4 o = (q == 0) ? A0 : (q == 1) ? A1 : (q == 2) ? A2 : A3;
        ushort4 h = make_ushort4(f2bf(o.x), f2bf(o.y), f2bf(o.z), f2bf(o.w));
        *reinterpret_cast<ushort4*>(outp + (size_t)node * 256 + q * 64 + m * 4) = h;
    } else {
        A0.x += A1.x + A2.x + A3.x;
        A0.y += A1.y + A2.y + A3.y;
        A0.z += A1.z + A2.z + A3.z;
        A0.w += A1.w + A2.w + A3.w;
        A0 = quad_reduce(A0);
        if (q == 0) {
            ushort4 h = make_ushort4(f2bf(A0.x), f2bf(A0.y), f2bf(A0.z), f2bf(A0.w));
            *reinterpret_cast<ushort4*>(outp + (size_t)node * 64 + m * 4) = h;
        }
    }
}

// ---------------------------------------------------------------------------
// RGCN transform via MFMA: OUT = relu(([Xb|AGGh] @ Bp) / deg), K = 320.
// (R17, proven.) Block = 4 waves x 16 rows; 10 K-steps x 4 col-frags from
// global; no LDS/barriers. Writes fp32 OUT (N x 64) + bf16 shadow OUTb.
// ---------------------------------------------------------------------------
__global__ __launch_bounds__(256) void rgcn_mfma(
    const unsigned short* __restrict__ Xb, const unsigned short* __restrict__ AGGh,
    const unsigned short* __restrict__ Bp, const int* __restrict__ rp2,
    float* __restrict__ OUT, unsigned short* __restrict__ OUTb, int N) {
    const int tid = threadIdx.x;
    const int w = tid >> 6, l = tid & 63;
    const int lr = l & 15, kg = l >> 4;
    const int rowA = blockIdx.x * 64 + w * 16 + lr;
    const bool okA = rowA < N;
    f32x4v acc0 = {0.f, 0.f, 0.f, 0.f};
    f32x4v acc1 = acc0, acc2 = acc0, acc3 = acc0;
    const unsigned short* xrow = Xb + (size_t)rowA * 64 + kg * 8;
    const unsigned short* arow = AGGh + (size_t)rowA * 256 + kg * 8;
    const unsigned short* bbase = Bp + (size_t)kg * 128 + lr * 8;
#pragma unroll
    for (int t = 0; t < 10; ++t) {
        short8 a = {0, 0, 0, 0, 0, 0, 0, 0};
        if (okA) {
            const unsigned short* pa = (t < 2) ? (xrow + t * 32) : (arow + (t - 2) * 32);
            a = *reinterpret_cast<const short8*>(pa);
        }
        short8 b0 = *reinterpret_cast<const short8*>(bbase + (size_t)t * 2048 + 0 * 512);
        short8 b1 = *reinterpret_cast<const short8*>(bbase + (size_t)t * 2048 + 1 * 512);
        short8 b2 = *reinterpret_cast<const short8*>(bbase + (size_t)t * 2048 + 2 * 512);
        short8 b3 = *reinterpret_cast<const short8*>(bbase + (size_t)t * 2048 + 3 * 512);
        acc0 = __builtin_amdgcn_mfma_f32_16x16x32_bf16(a, b0, acc0, 0, 0, 0);
        acc1 = __builtin_amdgcn_mfma_f32_16x16x32_bf16(a, b1, acc1, 0, 0, 0);
        acc2 = __builtin_amdgcn_mfma_f32_16x16x32_bf16(a, b2, acc2, 0, 0, 0);
        acc3 = __builtin_amdgcn_mfma_f32_16x16x32_bf16(a, b3, acc3, 0, 0, 0);
    }
    const int rbase = blockIdx.x * 64 + w * 16 + kg * 4;
#pragma unroll
    for (int j = 0; j < 4; ++j) {
        int row = rbase + j;
        if (row >= N) continue;
        float dg = fmaxf((float)(rp2[row * 4 + 4] - rp2[row * 4]), 1.f);
        float v0 = fmaxf(acc0[j] / dg, 0.f);
        float v1 = fmaxf(acc1[j] / dg, 0.f);
        float v2 = fmaxf(acc2[j] / dg, 0.f);
        float v3 = fmaxf(acc3[j] / dg, 0.f);
        size_t rb = (size_t)row * 64 + lr;
        OUT[rb + 0]  = v0;
        OUT[rb + 16] = v1;
        OUT[rb + 32] = v2;
        OUT[rb + 48] = v3;
        OUTb[rb + 0]  = f2bf(v0);
        OUTb[rb + 16] = f2bf(v1);
        OUTb[rb + 32] = f2bf(v2);
        OUTb[rb + 48] = f2bf(v3);
    }
}

// ---------------------------------------------------------------------------
// GroupEnhance via MFMA (R18, proven): acc = AGGb @ Pb (K=64);
// g = X + alpha*(acc/deg + bias).
// HEAD=0: writes g (fp32 OUT N x 64) + bf16 shadow. No LDS/barriers.
// HEAD=1: stages g into LDS in C/D order, then the proven vector head
//         mini-GEMM: OUT = g @ OW + ob (N x 32).
// ---------------------------------------------------------------------------
template <int HEAD>
__global__ __launch_bounds__(256) void group_mfma(
    const float* __restrict__ X, const unsigned short* __restrict__ AGGb,
    const unsigned short* __restrict__ Pb, const float* __restrict__ bias,
    const float* __restrict__ alphap, const int* __restrict__ rp2,
    const float* __restrict__ OW, const float* __restrict__ ob,
    float* __restrict__ OUT, unsigned short* __restrict__ OUTb, int N) {
    __shared__ float Gs[(HEAD ? 64 : 1)][68];
    __shared__ float Ws[(HEAD ? 64 : 1)][32];
    const int tid = threadIdx.x;
    const int w = tid >> 6, l = tid & 63;
    const int lr = l & 15, kg = l >> 4;
    const int rowA = blockIdx.x * 64 + w * 16 + lr;
    const bool okA = rowA < N;
    f32x4v acc0 = {0.f, 0.f, 0.f, 0.f};
    f32x4v acc1 = acc0, acc2 = acc0, acc3 = acc0;
    const unsigned short* arow = AGGb + (size_t)rowA * 64 + kg * 8;
    const unsigned short* bbase = Pb + (size_t)kg * 128 + lr * 8;
#pragma unroll
    for (int t = 0; t < 2; ++t) {
        short8 a = {0, 0, 0, 0, 0, 0, 0, 0};
        if (okA) a = *reinterpret_cast<const short8*>(arow + t * 32);
        short8 b0 = *reinterpret_cast<const short8*>(bbase + (size_t)t * 2048 + 0 * 512);
        short8 b1 = *reinterpret_cast<const short8*>(bbase + (size_t)t * 2048 + 1 * 512);
        short8 b2 = *reinterpret_cast<const short8*>(bbase + (size_t)t * 2048 + 2 * 512);
        short8 b3 = *reinterpret_cast<const short8*>(bbase + (size_t)t * 2048 + 3 * 512);
        acc0 = __builtin_amdgcn_mfma_f32_16x16x32_bf16(a, b0, acc0, 0, 0, 0);
        acc1 = __builtin_amdgcn_mfma_f32_16x16x32_bf16(a, b1, acc1, 0, 0, 0);
        acc2 = __builtin_amdgcn_mfma_f32_16x16x32_bf16(a, b2, acc2, 0, 0, 0);
        acc3 = __builtin_amdgcn_mfma_f32_16x16x32_bf16(a, b3, acc3, 0, 0, 0);
    }
    const float alpha = alphap[0];
    const int rbase = blockIdx.x * 64 + w * 16 + kg * 4;

    if (!HEAD) {
#pragma unroll
        for (int j = 0; j < 4; ++j) {
            int row = rbase + j;
            if (row >= N) continue;
            float dg = fmaxf((float)(rp2[row * 4 + 4] - rp2[row * 4]), 1.f);
            size_t rb = (size_t)row * 64 + lr;
            float v0 = X[rb + 0]  + alpha * (acc0[j] / dg + bias[lr + 0]);
            float v1 = X[rb + 16] + alpha * (acc1[j] / dg + bias[lr + 16]);
            float v2 = X[rb + 32] + alpha * (acc2[j] / dg + bias[lr + 32]);
            float v3 = X[rb + 48] + alpha * (acc3[j] / dg + bias[lr + 48]);
            OUT[rb + 0]  = v0;
            OUT[rb + 16] = v1;
            OUT[rb + 32] = v2;
            OUT[rb + 48] = v3;
            OUTb[rb + 0]  = f2bf(v0);
            OUTb[rb + 16] = f2bf(v1);
            OUTb[rb + 32] = f2bf(v2);
            OUTb[rb + 48] = f2bf(v3);
        }
        return;
    }

    // HEAD: stage g into Gs in C/D order, then vector head mini-GEMM.
#pragma unroll
    for (int j = 0; j < 4; ++j) {
        int row = rbase + j;
        float v0 = 0.f, v1 = 0.f, v2 = 0.f, v3 = 0.f;
        if (row < N) {
            float dg = fmaxf((float)(rp2[row * 4 + 4] - rp2[row * 4]), 1.f);
            size_t rb = (size_t)row * 64 + lr;
            v0 = X[rb + 0]  + alpha * (acc0[j] / dg + bias[lr + 0]);
            v1 = X[rb + 16] + alpha * (acc1[j] / dg + bias[lr + 16]);
            v2 = X[rb + 32] + alpha * (acc2[j] / dg + bias[lr + 32]);
            v3 = X[rb + 48] + alpha * (acc3[j] / dg + bias[lr + 48]);
        }
        int lrow = w * 16 + kg * 4 + j;
        Gs[lrow][lr + 0]  = v0;
        Gs[lrow][lr + 16] = v1;
        Gs[lrow][lr + 32] = v2;
        Gs[lrow][lr + 48] = v3;
    }
    // stage OW (64 x 32): 512 float4s, 2 per thread
#pragma unroll
    for (int t = 0; t < 2; ++t) {
        int idx = tid * 2 + t;
        int r = idx >> 3;
        int c4 = (idx & 7) << 2;
        *reinterpret_cast<float4*>(&Ws[r][c4]) =
            *reinterpret_cast<const float4*>(OW + (size_t)r * 32 + c4);
    }
    __syncthreads();
    const int tx = tid & 15, ty = tid >> 4;
    const int row0 = blockIdx.x * 64;
    float acc2h[4][2] = {};
#pragma unroll 8
    for (int k = 0; k < 64; ++k) {
        float b0 = Ws[k][tx * 2];
        float b1 = Ws[k][tx * 2 + 1];
#pragma unroll
        for (int i = 0; i < 4; ++i) {
            float a = Gs[ty * 4 + i][k];
            acc2h[i][0] += a * b0;
            acc2h[i][1] += a * b1;
        }
    }
#pragma unroll
    for (int i = 0; i < 4; ++i) {
        int vr = row0 + ty * 4 + i;
        if (vr >= N) continue;
#pragma unroll
        for (int j = 0; j < 2; ++j) {
            int col = tx * 2 + j;
            OUT[(size_t)vr * 32 + col] = acc2h[i][j] + ob[col];
        }
    }
}

extern "C" void kernel_launch(void* const* d_in, const int* in_sizes, int n_in,
                              void* d_out, int out_size, void* d_ws, size_t ws_size,
                              hipStream_t stream) {
    const float* x      = (const float*)d_in[0];
    const int*   ei     = (const int*)d_in[1];
    const int*   et     = (const int*)d_in[2];
    const float* ew     = (const float*)d_in[3];
    const float* W1     = (const float*)d_in[4];
    const float* W01    = (const float*)d_in[5];
    const float* alpha1 = (const float*)d_in[6];
    const float* projW1 = (const float*)d_in[7];
    const float* projb1 = (const float*)d_in[8];
    const float* W2     = (const float*)d_in[9];
    const float* W02    = (const float*)d_in[10];
    const float* alpha2 = (const float*)d_in[11];
    const float* projW2 = (const float*)d_in[12];
    const float* projb2 = (const float*)d_in[13];
    const float* outW   = (const float*)d_in[14];
    const float* outb   = (const float*)d_in[15];
    const int N = in_sizes[0] / 64;
    const int E = in_sizes[2];
    const int M = 4 * N;            // (dst, rel) segments
    const int NB = (N + 255) >> 8;  // 256-node dst buckets

    // workspace (4-byte units):
    // bcnt[1024] | bofs[1032] | bcur[1024] | rp2[M+1 (+pad)] | pw int2[E] |
    // aggRegion (16B-aligned, N*256 floats):
    //     [0,      N*128)  aggH   bf16 N x 256  (relation agg)
    //     [N*128,  N*160)  aggFb  bf16 N x 64   (group agg)
    //     [N*192,  N*224)  xb/gb  bf16 N x 64   (shadow: x, then g)
    //     [N*224,  N*256)  hb     bf16 N x 64   (shadow: h)
    //     (rec int2[E] aliases the front during CSR build only)
    // | h[N*64] | g[N*64] | wb1 bf16[20480] | wb2 bf16[20480]
    // | pb1 bf16[4096] | pb2 bf16[4096]
    int*   bcnt = (int*)d_ws;
    int*   bofs = bcnt + 1024;
    int*   bcur = bofs + 1032;
    int*   rp2  = bcur + 1024;
    int2*  pw   = (int2*)(rp2 + ((M + 2) & ~1));
    float* aggRegion = (float*)(((uintptr_t)(pw + E) + 15) & ~(uintptr_t)15);
    unsigned short* aggH = (unsigned short*)aggRegion;              // bf16 N x 256
    unsigned short* aggFb = (unsigned short*)(aggRegion + (size_t)N * 128);  // bf16 N x 64
    unsigned short* xb = (unsigned short*)(aggRegion + (size_t)N * 192);     // also gb
    unsigned short* hb = (unsigned short*)(aggRegion + (size_t)N * 224);
    int2*  rec = (int2*)aggRegion;        // alias: dead once gathers run
    float* hbuf = aggRegion + (size_t)N * 256;
    float* gbuf = hbuf + (size_t)N * 64;
    unsigned short* wb1 = (unsigned short*)(gbuf + (size_t)N * 64);  // packed bf16 320x64
    unsigned short* wb2 = wb1 + 20480;
    unsigned short* pb1 = wb2 + 20480;                               // packed bf16 64x64
    unsigned short* pb2 = pb1 + 4096;

    const int gatherBlocks = (N + 3) / 4;
    const int gemmBlocks = (N + 63) / 64;
    const int pBlocks = (E + PART_EPB - 1) / PART_EPB;

    // ---- CSR build + weight packing (once per call) ----
    hipMemsetAsync(bcnt, 0, 1024 * sizeof(int), stream);
    bucket_hist<<<pBlocks, 256, 0, stream>>>(ei, bcnt, E, NB);
    bucket_scan<<<1, 1024, 0, stream>>>(bcnt, bofs, bcur, NB, E);
    partition<<<pBlocks, 256, 0, stream>>>(ei, et, ew, bcur, rec, E, NB);
    bucket_fill<<<NB, 256, 0, stream>>>(rec, bofs, rp2, pw, N);
    cast_bf16<<<(N * 16 + 255) / 256, 256, 0, stream>>>(x, xb, N * 16);
    pack_w<<<80, 256, 0, stream>>>(W01, W1, wb1);
    pack_w<<<80, 256, 0, stream>>>(W02, W2, wb2);
    pack_w64<<<16, 256, 0, stream>>>(projW1, pb1);
    pack_w64<<<16, 256, 0, stream>>>(projW2, pb2);

    // ---- layer 1 ----
    gather_k<1><<<gatherBlocks, 256, 0, stream>>>(xb, rp2, pw, aggH, N);
    rgcn_mfma<<<gemmBlocks, 256, 0, stream>>>(xb, aggH, wb1, rp2, hbuf, hb, N);
    gather_k<0><<<gatherBlocks, 256, 0, stream>>>(hb, rp2, pw, aggFb, N);
    group_mfma<0><<<gemmBlocks, 256, 0, stream>>>(hbuf, aggFb, pb1, projb1, alpha1, rp2,
                                                  nullptr, nullptr, gbuf, xb /*gb*/, N);

    // ---- layer 2 ----
    gather_k<1><<<gatherBlocks, 256, 0, stream>>>(xb /*gb*/, rp2, pw, aggH, N);
    rgcn_mfma<<<gemmBlocks, 256, 0, stream>>>(xb /*gb*/, aggH, wb2, rp2, hbuf, hb, N);
    gather_k<0><<<gatherBlocks, 256, 0, stream>>>(hb, rp2, pw, aggFb, N);
    // group + head fused: writes N x 32 output directly
    group_mfma<1><<<gemmBlocks, 256, 0, stream>>>(hbuf, aggFb, pb2, projb2, alpha2, rp2,
                                                  outW, outb, (float*)d_out, nullptr, N);
}

// Round 20
// 346.388 us; speedup vs baseline: 1.0036x; 1.0036x over previous
//
#include <hip/hip_runtime.h>

// ---------------------------------------------------------------------------
// MR_GNN: 2x (RGCN + GroupEnhance) + linear head.
// R20 = R18 verbatim (best measured: 338.9us, absmax 5.7e-6). R19's CSR
// rework (EPB 1024 + packed records) regressed net +9us: partition got
// faster but hist's doubled grid + 2x reserve atomics + record decode cost
// more than it saved. All components now probed from both directions:
//  - gathers at the ~4TB/s random-gather ceiling (R8/R9/R10 all regressed),
//  - CSR build: EPB 16384 x, 2048 ok, 1024 x,
//  - GEMMs on MFMA (R17/R18), vector-GEMM restructures R14/R15/R16 all x.
// Pipeline: radix CSR build + bf16 shadow tables; per layer:
// gather_rel(bf16) -> rgcn_mfma(K=320, no LDS/barriers) ->
// gather_plain(bf16) -> group_mfma (HEAD=1 fuses the output head).
// ---------------------------------------------------------------------------

#define PART_EPB 2048  // edges per partition/hist block (256 thr x 8)

using short8 = __attribute__((ext_vector_type(8))) short;
using f32x4v = __attribute__((ext_vector_type(4))) float;

// ---- CSR build, pass A1: per-bucket edge counts (bucket = dst >> 8) ----
__global__ __launch_bounds__(256) void bucket_hist(const int* __restrict__ ei,
                                                   int* __restrict__ bcnt,
                                                   int E, int NB) {
    __shared__ int h[1024];
    for (int i = threadIdx.x; i < 1024; i += 256) h[i] = 0;
    __syncthreads();
    int base = blockIdx.x * PART_EPB;
#pragma unroll
    for (int k = 0; k < PART_EPB / 256; ++k) {
        int e = base + k * 256 + threadIdx.x;
        if (e < E) atomicAdd(&h[ei[E + e] >> 8], 1);
    }
    __syncthreads();
    for (int i = threadIdx.x; i < NB; i += 256)
        if (h[i]) atomicAdd(&bcnt[i], h[i]);
}

// ---- pass A-scan: exclusive scan of NB (<=1024) bucket counts ----
__global__ __launch_bounds__(1024) void bucket_scan(const int* __restrict__ bcnt,
                                                    int* __restrict__ bofs,
                                                    int* __restrict__ bcur,
                                                    int NB, int E) {
    __shared__ int lds[1024];
    int tid = threadIdx.x;
    int v = (tid < NB) ? bcnt[tid] : 0;
    lds[tid] = v;
    __syncthreads();
    int acc = v;
    for (int off = 1; off < 1024; off <<= 1) {
        int t = (tid >= off) ? lds[tid - off] : 0;
        __syncthreads();
        acc += t;
        lds[tid] = acc;
        __syncthreads();
    }
    int excl = acc - v;
    if (tid < NB) { bofs[tid] = excl; bcur[tid] = excl; }
    if (tid == 0) bofs[NB] = E;
}

// ---- pass A2: block-aggregated partition into bucket streams ----
__global__ __launch_bounds__(256) void partition(const int* __restrict__ ei,
                                                 const int* __restrict__ et,
                                                 const float* __restrict__ ew,
                                                 int* __restrict__ gcur,
                                                 int2* __restrict__ recA,
                                                 int* __restrict__ recB,
                                                 int E, int NB) {
    __shared__ int hist[1024];
    __shared__ int base[1024];
    const int tid = threadIdx.x;
    const int blockBase = blockIdx.x * PART_EPB;
    for (int i = tid; i < 1024; i += 256) hist[i] = 0;
    __syncthreads();
#pragma unroll
    for (int k = 0; k < PART_EPB / 256; ++k) {
        int e = blockBase + k * 256 + tid;
        if (e < E) atomicAdd(&hist[ei[E + e] >> 8], 1);
    }
    __syncthreads();
    for (int i = tid; i < NB; i += 256) {
        int h = hist[i];
        base[i] = h ? atomicAdd(&gcur[i], h) : 0;
    }
    __syncthreads();
    for (int i = tid; i < 1024; i += 256) hist[i] = 0;  // reuse as run cursor
    __syncthreads();
#pragma unroll
    for (int k = 0; k < PART_EPB / 256; ++k) {
        int e = blockBase + k * 256 + tid;
        if (e >= E) continue;
        int dst = ei[E + e];
        int b = dst >> 8;
        int pos = base[b] + atomicAdd(&hist[b], 1);
        recA[pos] = make_int2(ei[e], __float_as_int(ew[e]));
        recB[pos] = dst * 4 + et[e];
    }
}

// ---- pass B: per-bucket (node,rel) hist + scan in LDS, write rp2 + pw ----
__global__ __launch_bounds__(256) void bucket_fill(
    const int2* __restrict__ recA, const int* __restrict__ recB,
    const int* __restrict__ bofs, int* __restrict__ rp2, int2* __restrict__ pw,
    int N) {
    __shared__ int cnt[1024];
    __shared__ int cur[1024];
    __shared__ int wsum[4];
    const int b = blockIdx.x;
    const int tid = threadIdx.x;
    const int beg = bofs[b], end = bofs[b + 1];
    const int rebase = b << 10;  // base index in (dst*4+rel) space
    for (int j = 0; j < 4; ++j) cnt[tid * 4 + j] = 0;
    __syncthreads();
    for (int i = beg + tid; i < end; i += 256)
        atomicAdd(&cnt[recB[i] - rebase], 1);
    __syncthreads();
    int v[4];
    int s = 0;
#pragma unroll
    for (int j = 0; j < 4; ++j) { v[j] = cnt[tid * 4 + j]; s += v[j]; }
    int lane = tid & 63, wid = tid >> 6;
    int ws = s;
#pragma unroll
    for (int off = 1; off < 64; off <<= 1) {
        int t = __shfl_up(ws, off);
        if (lane >= off) ws += t;
    }
    if (lane == 63) wsum[wid] = ws;
    __syncthreads();
    int wb = 0;
    for (int w = 0; w < wid; ++w) wb += wsum[w];
    int run = beg + wb + ws - s;
#pragma unroll
    for (int j = 0; j < 4; ++j) {
        int idx = rebase + tid * 4 + j;
        if (idx <= 4 * N) rp2[idx] = run;
        cur[tid * 4 + j] = run;
        run += v[j];
    }
    __syncthreads();
    for (int i = beg + tid; i < end; i += 256) {
        int l = recB[i] - rebase;
        int p = atomicAdd(&cur[l], 1);
        pw[p] = recA[i];
    }
}

__device__ __forceinline__ float4 quad_reduce(float4 a) {
#pragma unroll
    for (int off = 16; off < 64; off <<= 1) {
        a.x += __shfl_xor(a.x, off);
        a.y += __shfl_xor(a.y, off);
        a.z += __shfl_xor(a.z, off);
        a.w += __shfl_xor(a.w, off);
    }
    return a;
}

__device__ __forceinline__ void fma4(float4& a, float w, const float4& x) {
    a.x += w * x.x; a.y += w * x.y; a.z += w * x.z; a.w += w * x.w;
}

__device__ __forceinline__ unsigned short f2bf(float f) {
    unsigned u = __float_as_uint(f);
    unsigned r = u + 0x7fffu + ((u >> 16) & 1u);  // round-to-nearest-even
    return (unsigned short)(r >> 16);
}

__device__ __forceinline__ float bf2f(unsigned short h) {
    return __uint_as_float(((unsigned)h) << 16);
}

__device__ __forceinline__ float4 bf2f4(ushort4 h) {
    return make_float4(bf2f(h.x), bf2f(h.y), bf2f(h.z), bf2f(h.w));
}

// ---- fp32 -> bf16 table cast (for x; sequential, ~2us) ----
__global__ __launch_bounds__(256) void cast_bf16(const float* __restrict__ in,
                                                 unsigned short* __restrict__ out,
                                                 int n4) {
    int i = blockIdx.x * 256 + threadIdx.x;
    if (i >= n4) return;
    float4 v = reinterpret_cast<const float4*>(in)[i];
    reinterpret_cast<ushort4*>(out)[i] =
        make_ushort4(f2bf(v.x), f2bf(v.y), f2bf(v.z), f2bf(v.w));
}

// ---- pack B_cat = [W0 (64x64); Wr (4x64x64)] (K=320 x N=64) into bf16
// MFMA B-fragment order: out[((t*4+n4)*4+kg)*128 + col*8 + j] =
// bf16(B_cat[t*32+kg*8+j][n4*16+col]).  20480 elements. ----
__global__ __launch_bounds__(256) void pack_w(const float* __restrict__ W0,
                                              const float* __restrict__ Wr,
                                              unsigned short* __restrict__ out) {
    int i = blockIdx.x * 256 + threadIdx.x;
    if (i >= 20480) return;
    int j = i & 7, col = (i >> 3) & 15, kg = (i >> 7) & 3, n4 = (i >> 9) & 3, t = i >> 11;
    int k = t * 32 + kg * 8 + j;
    int n = n4 * 16 + col;
    float v = (k < 64) ? W0[k * 64 + n] : Wr[(size_t)(k - 64) * 64 + n];
    out[i] = f2bf(v);
}

// ---- same pack for a single 64x64 weight (K=64): 4096 elements ----
__global__ __launch_bounds__(256) void pack_w64(const float* __restrict__ W,
                                                unsigned short* __restrict__ out) {
    int i = blockIdx.x * 256 + threadIdx.x;
    if (i >= 4096) return;
    int j = i & 7, col = (i >> 3) & 15, kg = (i >> 7) & 3, n4 = (i >> 9) & 3, t = i >> 11;
    int k = t * 32 + kg * 8 + j;
    int n = n4 * 16 + col;
    out[i] = f2bf(W[k * 64 + n]);
}

// ---------------------------------------------------------------------------
// Unified-range gather (R7 structure; bf16 input table; proven in R13).
// REL=1: masked per-relation accumulators -> bf16 out (ushort N x 256).
// REL=0: 4 chains summed -> bf16 out (ushort N x 64).
// ---------------------------------------------------------------------------
template <int REL>
__global__ __launch_bounds__(256) void gather_k(
    const unsigned short* __restrict__ Xb, const int* __restrict__ rp2,
    const int2* __restrict__ pw, unsigned short* __restrict__ outp, int N) {
    int node = blockIdx.x * 4 + (threadIdx.x >> 6);
    if (node >= N) return;
    int lane = threadIdx.x & 63;
    int q = lane >> 4, m = lane & 15;
    const int4 sv = *reinterpret_cast<const int4*>(rp2 + node * 4);
    const int s0 = sv.x, s1 = sv.y, s2 = sv.z, s3 = sv.w;
    const int s4 = rp2[node * 4 + 4];
    float4 A0 = make_float4(0.f, 0.f, 0.f, 0.f);
    float4 A1 = make_float4(0.f, 0.f, 0.f, 0.f);
    float4 A2 = make_float4(0.f, 0.f, 0.f, 0.f);
    float4 A3 = make_float4(0.f, 0.f, 0.f, 0.f);

    auto accum = [&](int idx, int slot, int2 e, const float4& xv) {
        float w = __int_as_float(e.y);
        if (REL) {
            fma4(A0, (idx < s1) ? w : 0.f, xv);
            fma4(A1, (idx >= s1 && idx < s2) ? w : 0.f, xv);
            fma4(A2, (idx >= s2 && idx < s3) ? w : 0.f, xv);
            fma4(A3, (idx >= s3) ? w : 0.f, xv);
        } else {
            if (slot == 0) fma4(A0, w, xv);
            else if (slot == 1) fma4(A1, w, xv);
            else if (slot == 2) fma4(A2, w, xv);
            else fma4(A3, w, xv);
        }
    };

    int i = s0 + q;
    for (; i + 12 < s4; i += 16) {  // 4 gathers in flight
        int2 e0 = pw[i];
        int2 e1 = pw[i + 4];
        int2 e2 = pw[i + 8];
        int2 e3 = pw[i + 12];
        ushort4 h0 = *reinterpret_cast<const ushort4*>(Xb + (size_t)e0.x * 64 + m * 4);
        ushort4 h1 = *reinterpret_cast<const ushort4*>(Xb + (size_t)e1.x * 64 + m * 4);
        ushort4 h2 = *reinterpret_cast<const ushort4*>(Xb + (size_t)e2.x * 64 + m * 4);
        ushort4 h3 = *reinterpret_cast<const ushort4*>(Xb + (size_t)e3.x * 64 + m * 4);
        accum(i, 0, e0, bf2f4(h0));
        accum(i + 4, 1, e1, bf2f4(h1));
        accum(i + 8, 2, e2, bf2f4(h2));
        accum(i + 12, 3, e3, bf2f4(h3));
    }
    for (; i + 4 < s4; i += 8) {  // 2 in flight
        int2 e0 = pw[i];
        int2 e1 = pw[i + 4];
        ushort4 h0 = *reinterpret_cast<const ushort4*>(Xb + (size_t)e0.x * 64 + m * 4);
        ushort4 h1 = *reinterpret_cast<const ushort4*>(Xb + (size_t)e1.x * 64 + m * 4);
        accum(i, 0, e0, bf2f4(h0));
        accum(i + 4, 1, e1, bf2f4(h1));
    }
    if (i < s4) {
        int2 e0 = pw[i];
        ushort4 h0 = *reinterpret_cast<const ushort4*>(Xb + (size_t)e0.x * 64 + m * 4);
        accum(i, 0, e0, bf2f4(h0));
    }

    if (REL) {
        A0 = quad_reduce(A0);
        A1 = quad_reduce(A1);
        A2 = quad_reduce(A2);
        A3 = quad_reduce(A3);
        float4 o = (q == 0) ? A0 : (q == 1) ? A1 : (q == 2) ? A2 : A3;
        ushort4 h = make_ushort4(f2bf(o.x), f2bf(o.y), f2bf(o.z), f2bf(o.w));
        *reinterpret_cast<ushort4*>(outp + (size_t)node * 256 + q * 64 + m * 4) = h;
    } else {
        A0.x += A1.x + A2.x + A3.x;
        A0.y += A1.y + A2.y + A3.y;
        A0.z += A1.z + A2.z + A3.z;
        A0.w += A1.w + A2.w + A3.w;
        A0 = quad_reduce(A0);
        if (q == 0) {
            ushort4 h = make_ushort4(f2bf(A0.x), f2bf(A0.y), f2bf(A0.z), f2bf(A0.w));
            *reinterpret_cast<ushort4*>(outp + (size_t)node * 64 + m * 4) = h;
        }
    }
}

// ---------------------------------------------------------------------------
// RGCN transform via MFMA: OUT = relu(([Xb|AGGh] @ Bp) / deg), K = 320.
// (R17, proven.) Block = 4 waves x 16 rows; 10 K-steps x 4 col-frags from
// global; no LDS/barriers. Writes fp32 OUT (N x 64) + bf16 shadow OUTb.
// ---------------------------------------------------------------------------
__global__ __launch_bounds__(256) void rgcn_mfma(
    const unsigned short* __restrict__ Xb, const unsigned short* __restrict__ AGGh,
    const unsigned short* __restrict__ Bp, const int* __restrict__ rp2,
    float* __restrict__ OUT, unsigned short* __restrict__ OUTb, int N) {
    const int tid = threadIdx.x;
    const int w = tid >> 6, l = tid & 63;
    const int lr = l & 15, kg = l >> 4;
    const int rowA = blockIdx.x * 64 + w * 16 + lr;
    const bool okA = rowA < N;
    f32x4v acc0 = {0.f, 0.f, 0.f, 0.f};
    f32x4v acc1 = acc0, acc2 = acc0, acc3 = acc0;
    const unsigned short* xrow = Xb + (size_t)rowA * 64 + kg * 8;
    const unsigned short* arow = AGGh + (size_t)rowA * 256 + kg * 8;
    const unsigned short* bbase = Bp + (size_t)kg * 128 + lr * 8;
#pragma unroll
    for (int t = 0; t < 10; ++t) {
        short8 a = {0, 0, 0, 0, 0, 0, 0, 0};
        if (okA) {
            const unsigned short* pa = (t < 2) ? (xrow + t * 32) : (arow + (t - 2) * 32);
            a = *reinterpret_cast<const short8*>(pa);
        }
        short8 b0 = *reinterpret_cast<const short8*>(bbase + (size_t)t * 2048 + 0 * 512);
        short8 b1 = *reinterpret_cast<const short8*>(bbase + (size_t)t * 2048 + 1 * 512);
        short8 b2 = *reinterpret_cast<const short8*>(bbase + (size_t)t * 2048 + 2 * 512);
        short8 b3 = *reinterpret_cast<const short8*>(bbase + (size_t)t * 2048 + 3 * 512);
        acc0 = __builtin_amdgcn_mfma_f32_16x16x32_bf16(a, b0, acc0, 0, 0, 0);
        acc1 = __builtin_amdgcn_mfma_f32_16x16x32_bf16(a, b1, acc1, 0, 0, 0);
        acc2 = __builtin_amdgcn_mfma_f32_16x16x32_bf16(a, b2, acc2, 0, 0, 0);
        acc3 = __builtin_amdgcn_mfma_f32_16x16x32_bf16(a, b3, acc3, 0, 0, 0);
    }
    const int rbase = blockIdx.x * 64 + w * 16 + kg * 4;
#pragma unroll
    for (int j = 0; j < 4; ++j) {
        int row = rbase + j;
        if (row >= N) continue;
        float dg = fmaxf((float)(rp2[row * 4 + 4] - rp2[row * 4]), 1.f);
        float v0 = fmaxf(acc0[j] / dg, 0.f);
        float v1 = fmaxf(acc1[j] / dg, 0.f);
        float v2 = fmaxf(acc2[j] / dg, 0.f);
        float v3 = fmaxf(acc3[j] / dg, 0.f);
        size_t rb = (size_t)row * 64 + lr;
        OUT[rb + 0]  = v0;
        OUT[rb + 16] = v1;
        OUT[rb + 32] = v2;
        OUT[rb + 48] = v3;
        OUTb[rb + 0]  = f2bf(v0);
        OUTb[rb + 16] = f2bf(v1);
        OUTb[rb + 32] = f2bf(v2);
        OUTb[rb + 48] = f2bf(v3);
    }
}

// ---------------------------------------------------------------------------
// GroupEnhance via MFMA (R18, proven): acc = AGGb @ Pb (K=64);
// g = X + alpha*(acc/deg + bias).
// HEAD=0: writes g (fp32 OUT N x 64) + bf16 shadow. No LDS/barriers.
// HEAD=1: stages g into LDS in C/D order, then the proven vector head
//         mini-GEMM: OUT = g @ OW + ob (N x 32).
// ---------------------------------------------------------------------------
template <int HEAD>
__global__ __launch_bounds__(256) void group_mfma(
    const float* __restrict__ X, const unsigned short* __restrict__ AGGb,
    const unsigned short* __restrict__ Pb, const float* __restrict__ bias,
    const float* __restrict__ alphap, const int* __restrict__ rp2,
    const float* __restrict__ OW, const float* __restrict__ ob,
    float* __restrict__ OUT, unsigned short* __restrict__ OUTb, int N) {
    __shared__ float Gs[(HEAD ? 64 : 1)][68];
    __shared__ float Ws[(HEAD ? 64 : 1)][32];
    const int tid = threadIdx.x;
    const int w = tid >> 6, l = tid & 63;
    const int lr = l & 15, kg = l >> 4;
    const int rowA = blockIdx.x * 64 + w * 16 + lr;
    const bool okA = rowA < N;
    f32x4v acc0 = {0.f, 0.f, 0.f, 0.f};
    f32x4v acc1 = acc0, acc2 = acc0, acc3 = acc0;
    const unsigned short* arow = AGGb + (size_t)rowA * 64 + kg * 8;
    const unsigned short* bbase = Pb + (size_t)kg * 128 + lr * 8;
#pragma unroll
    for (int t = 0; t < 2; ++t) {
        short8 a = {0, 0, 0, 0, 0, 0, 0, 0};
        if (okA) a = *reinterpret_cast<const short8*>(arow + t * 32);
        short8 b0 = *reinterpret_cast<const short8*>(bbase + (size_t)t * 2048 + 0 * 512);
        short8 b1 = *reinterpret_cast<const short8*>(bbase + (size_t)t * 2048 + 1 * 512);
        short8 b2 = *reinterpret_cast<const short8*>(bbase + (size_t)t * 2048 + 2 * 512);
        short8 b3 = *reinterpret_cast<const short8*>(bbase + (size_t)t * 2048 + 3 * 512);
        acc0 = __builtin_amdgcn_mfma_f32_16x16x32_bf16(a, b0, acc0, 0, 0, 0);
        acc1 = __builtin_amdgcn_mfma_f32_16x16x32_bf16(a, b1, acc1, 0, 0, 0);
        acc2 = __builtin_amdgcn_mfma_f32_16x16x32_bf16(a, b2, acc2, 0, 0, 0);
        acc3 = __builtin_amdgcn_mfma_f32_16x16x32_bf16(a, b3, acc3, 0, 0, 0);
    }
    const float alpha = alphap[0];
    const int rbase = blockIdx.x * 64 + w * 16 + kg * 4;

    if (!HEAD) {
#pragma unroll
        for (int j = 0; j < 4; ++j) {
            int row = rbase + j;
            if (row >= N) continue;
            float dg = fmaxf((float)(rp2[row * 4 + 4] - rp2[row * 4]), 1.f);
            size_t rb = (size_t)row * 64 + lr;
            float v0 = X[rb + 0]  + alpha * (acc0[j] / dg + bias[lr + 0]);
            float v1 = X[rb + 16] + alpha * (acc1[j] / dg + bias[lr + 16]);
            float v2 = X[rb + 32] + alpha * (acc2[j] / dg + bias[lr + 32]);
            float v3 = X[rb + 48] + alpha * (acc3[j] / dg + bias[lr + 48]);
            OUT[rb + 0]  = v0;
            OUT[rb + 16] = v1;
            OUT[rb + 32] = v2;
            OUT[rb + 48] = v3;
            OUTb[rb + 0]  = f2bf(v0);
            OUTb[rb + 16] = f2bf(v1);
            OUTb[rb + 32] = f2bf(v2);
            OUTb[rb + 48] = f2bf(v3);
        }
        return;
    }

    // HEAD: stage g into Gs in C/D order, then vector head mini-GEMM.
#pragma unroll
    for (int j = 0; j < 4; ++j) {
        int row = rbase + j;
        float v0 = 0.f, v1 = 0.f, v2 = 0.f, v3 = 0.f;
        if (row < N) {
            float dg = fmaxf((float)(rp2[row * 4 + 4] - rp2[row * 4]), 1.f);
            size_t rb = (size_t)row * 64 + lr;
            v0 = X[rb + 0]  + alpha * (acc0[j] / dg + bias[lr + 0]);
            v1 = X[rb + 16] + alpha * (acc1[j] / dg + bias[lr + 16]);
            v2 = X[rb + 32] + alpha * (acc2[j] / dg + bias[lr + 32]);
            v3 = X[rb + 48] + alpha * (acc3[j] / dg + bias[lr + 48]);
        }
        int lrow = w * 16 + kg * 4 + j;
        Gs[lrow][lr + 0]  = v0;
        Gs[lrow][lr + 16] = v1;
        Gs[lrow][lr + 32] = v2;
        Gs[lrow][lr + 48] = v3;
    }
    // stage OW (64 x 32): 512 float4s, 2 per thread
#pragma unroll
    for (int t = 0; t < 2; ++t) {
        int idx = tid * 2 + t;
        int r = idx >> 3;
        int c4 = (idx & 7) << 2;
        *reinterpret_cast<float4*>(&Ws[r][c4]) =
            *reinterpret_cast<const float4*>(OW + (size_t)r * 32 + c4);
    }
    __syncthreads();
    const int tx = tid & 15, ty = tid >> 4;
    const int row0 = blockIdx.x * 64;
    float acc2h[4][2] = {};
#pragma unroll 8
    for (int k = 0; k < 64; ++k) {
        float b0 = Ws[k][tx * 2];
        float b1 = Ws[k][tx * 2 + 1];
#pragma unroll
        for (int i = 0; i < 4; ++i) {
            float a = Gs[ty * 4 + i][k];
            acc2h[i][0] += a * b0;
            acc2h[i][1] += a * b1;
        }
    }
#pragma unroll
    for (int i = 0; i < 4; ++i) {
        int vr = row0 + ty * 4 + i;
        if (vr >= N) continue;
#pragma unroll
        for (int j = 0; j < 2; ++j) {
            int col = tx * 2 + j;
            OUT[(size_t)vr * 32 + col] = acc2h[i][j] + ob[col];
        }
    }
}

extern "C" void kernel_launch(void* const* d_in, const int* in_sizes, int n_in,
                              void* d_out, int out_size, void* d_ws, size_t ws_size,
                              hipStream_t stream) {
    const float* x      = (const float*)d_in[0];
    const int*   ei     = (const int*)d_in[1];
    const int*   et     = (const int*)d_in[2];
    const float* ew     = (const float*)d_in[3];
    const float* W1     = (const float*)d_in[4];
    const float* W01    = (const float*)d_in[5];
    const float* alpha1 = (const float*)d_in[6];
    const float* projW1 = (const float*)d_in[7];
    const float* projb1 = (const float*)d_in[8];
    const float* W2     = (const float*)d_in[9];
    const float* W02    = (const float*)d_in[10];
    const float* alpha2 = (const float*)d_in[11];
    const float* projW2 = (const float*)d_in[12];
    const float* projb2 = (const float*)d_in[13];
    const float* outW   = (const float*)d_in[14];
    const float* outb   = (const float*)d_in[15];
    const int N = in_sizes[0] / 64;
    const int E = in_sizes[2];
    const int M = 4 * N;            // (dst, rel) segments
    const int NB = (N + 255) >> 8;  // 256-node dst buckets

    // workspace (4-byte units):
    // bcnt[1024] | bofs[1032] | bcur[1024] | rp2[M+1 (+pad)] | pw int2[E] |
    // aggRegion (16B-aligned, N*256 floats):
    //     [0,      N*128)  aggH   bf16 N x 256  (relation agg)
    //     [N*128,  N*160)  aggFb  bf16 N x 64   (group agg)
    //     [N*192,  N*224)  xb/gb  bf16 N x 64   (shadow: x, then g)
    //     [N*224,  N*256)  hb     bf16 N x 64   (shadow: h)
    //     (recA int2[E] + recB int[E] alias the front during CSR build only)
    // | h[N*64] | g[N*64] | wb1 bf16[20480] | wb2 bf16[20480]
    // | pb1 bf16[4096] | pb2 bf16[4096]
    int*   bcnt = (int*)d_ws;
    int*   bofs = bcnt + 1024;
    int*   bcur = bofs + 1032;
    int*   rp2  = bcur + 1024;
    int2*  pw   = (int2*)(rp2 + ((M + 2) & ~1));
    float* aggRegion = (float*)(((uintptr_t)(pw + E) + 15) & ~(uintptr_t)15);
    unsigned short* aggH = (unsigned short*)aggRegion;              // bf16 N x 256
    unsigned short* aggFb = (unsigned short*)(aggRegion + (size_t)N * 128);  // bf16 N x 64
    unsigned short* xb = (unsigned short*)(aggRegion + (size_t)N * 192);     // also gb
    unsigned short* hb = (unsigned short*)(aggRegion + (size_t)N * 224);
    int2*  recA = (int2*)aggRegion;       // alias: dead once gathers run
    int*   recB = (int*)(recA + E);
    float* hbuf = aggRegion + (size_t)N * 256;
    float* gbuf = hbuf + (size_t)N * 64;
    unsigned short* wb1 = (unsigned short*)(gbuf + (size_t)N * 64);  // packed bf16 320x64
    unsigned short* wb2 = wb1 + 20480;
    unsigned short* pb1 = wb2 + 20480;                               // packed bf16 64x64
    unsigned short* pb2 = pb1 + 4096;

    const int gatherBlocks = (N + 3) / 4;
    const int gemmBlocks = (N + 63) / 64;
    const int pBlocks = (E + PART_EPB - 1) / PART_EPB;

    // ---- CSR build + weight packing (once per call) ----
    hipMemsetAsync(bcnt, 0, 1024 * sizeof(int), stream);
    bucket_hist<<<pBlocks, 256, 0, stream>>>(ei, bcnt, E, NB);
    bucket_scan<<<1, 1024, 0, stream>>>(bcnt, bofs, bcur, NB, E);
    partition<<<pBlocks, 256, 0, stream>>>(ei, et, ew, bcur, recA, recB, E, NB);
    bucket_fill<<<NB, 256, 0, stream>>>(recA, recB, bofs, rp2, pw, N);
    cast_bf16<<<(N * 16 + 255) / 256, 256, 0, stream>>>(x, xb, N * 16);
    pack_w<<<80, 256, 0, stream>>>(W01, W1, wb1);
    pack_w<<<80, 256, 0, stream>>>(W02, W2, wb2);
    pack_w64<<<16, 256, 0, stream>>>(projW1, pb1);
    pack_w64<<<16, 256, 0, stream>>>(projW2, pb2);

    // ---- layer 1 ----
    gather_k<1><<<gatherBlocks, 256, 0, stream>>>(xb, rp2, pw, aggH, N);
    rgcn_mfma<<<gemmBlocks, 256, 0, stream>>>(xb, aggH, wb1, rp2, hbuf, hb, N);
    gather_k<0><<<gatherBlocks, 256, 0, stream>>>(hb, rp2, pw, aggFb, N);
    group_mfma<0><<<gemmBlocks, 256, 0, stream>>>(hbuf, aggFb, pb1, projb1, alpha1, rp2,
                                                  nullptr, nullptr, gbuf, xb /*gb*/, N);

    // ---- layer 2 ----
    gather_k<1><<<gatherBlocks, 256, 0, stream>>>(xb /*gb*/, rp2, pw, aggH, N);
    rgcn_mfma<<<gemmBlocks, 256, 0, stream>>>(xb /*gb*/, aggH, wb2, rp2, hbuf, hb, N);
    gather_k<0><<<gatherBlocks, 256, 0, stream>>>(hb, rp2, pw, aggFb, N);
    // group + head fused: writes N x 32 output directly
    group_mfma<1><<<gemmBlocks, 256, 0, stream>>>(hbuf, aggFb, pb2, projb2, alpha2, rp2,
                                                  outW, outb, (float*)d_out, nullptr, N);
}